// Round 1
// baseline (1858.830 us; speedup 1.0000x reference)
//
#include <hip/hip_runtime.h>

#define MTOT 25088
#define DMODEL 768
#define NH 12
#define WIN 49
#define NLAYER 2

typedef short bf16x8 __attribute__((ext_vector_type(8)));
typedef float f32x4 __attribute__((ext_vector_type(4)));
typedef unsigned short u16x4 __attribute__((ext_vector_type(4)));

__device__ __forceinline__ float bf2f(short s) {
    return __uint_as_float(((unsigned)(unsigned short)s) << 16);
}
__device__ __forceinline__ short f2b(float f) {
    unsigned x = __float_as_uint(f);
    unsigned r = x + 0x7FFFu + ((x >> 16) & 1u);
    return (short)(r >> 16);
}

// ---------------- fp32 -> bf16 weight conversion ----------------
__global__ __launch_bounds__(256) void cvt_f32_to_bf16(const float* __restrict__ in,
                                                       short* __restrict__ out, int n8) {
    int i = blockIdx.x * 256 + threadIdx.x;
    if (i >= n8) return;
    const float4* p = (const float4*)in + (size_t)i * 2;
    float4 a = p[0], b = p[1];
    bf16x8 o;
    o[0] = f2b(a.x); o[1] = f2b(a.y); o[2] = f2b(a.z); o[3] = f2b(a.w);
    o[4] = f2b(b.x); o[5] = f2b(b.y); o[6] = f2b(b.z); o[7] = f2b(b.w);
    *((bf16x8*)out + i) = o;
}

// ---------------- LayerNorm (fp32 in, bf16 out), 1 wave per row ----------------
__global__ __launch_bounds__(256) void ln_to_bf16(const float* __restrict__ h,
                                                  const float* __restrict__ w,
                                                  const float* __restrict__ b,
                                                  short* __restrict__ y) {
    int wave = threadIdx.x >> 6, lane = threadIdx.x & 63;
    int row = blockIdx.x * 4 + wave;
    const float4* hp = (const float4*)(h + (size_t)row * DMODEL);
    float4 v[3];
    float s = 0.f, s2 = 0.f;
#pragma unroll
    for (int c = 0; c < 3; c++) {
        v[c] = hp[lane + 64 * c];
        s += v[c].x + v[c].y + v[c].z + v[c].w;
        s2 += v[c].x * v[c].x + v[c].y * v[c].y + v[c].z * v[c].z + v[c].w * v[c].w;
    }
#pragma unroll
    for (int off = 32; off > 0; off >>= 1) {
        s += __shfl_xor(s, off);
        s2 += __shfl_xor(s2, off);
    }
    float mean = s * (1.f / DMODEL);
    float var = s2 * (1.f / DMODEL) - mean * mean;
    float rstd = rsqrtf(var + 1e-5f);
#pragma unroll
    for (int c = 0; c < 3; c++) {
        float4 wv = ((const float4*)w)[lane + 64 * c];
        float4 bv = ((const float4*)b)[lane + 64 * c];
        u16x4 o;
        o[0] = (unsigned short)f2b((v[c].x - mean) * rstd * wv.x + bv.x);
        o[1] = (unsigned short)f2b((v[c].y - mean) * rstd * wv.y + bv.y);
        o[2] = (unsigned short)f2b((v[c].z - mean) * rstd * wv.z + bv.z);
        o[3] = (unsigned short)f2b((v[c].w - mean) * rstd * wv.w + bv.w);
        *(u16x4*)(y + (size_t)row * DMODEL + (size_t)(lane + 64 * c) * 4) = o;
    }
}

// ---------------- GEMM: C[M,N] = A[M,K](bf16) @ B[N,K](bf16)^T + bias, epilogues ----------------
// EPI 0: out bf16 = v + bias
// EPI 1: out fp32 (in-place residual) += v + bias
// EPI 2: out bf16 = gelu_exact(v + bias)
template <int EPI>
__global__ __launch_bounds__(256, 2)
void gemm_bt(const short* __restrict__ A, const short* __restrict__ B,
             const float* __restrict__ bias, void* __restrict__ C,
             int M, int N, int K) {
    __shared__ __align__(16) short As[128 * 32];
    __shared__ __align__(16) short Bs[128 * 32];
    const int tid = threadIdx.x;
    const int wave = tid >> 6, lane = tid & 63;
    const int row0 = blockIdx.y * 128, col0 = blockIdx.x * 128;
    const int wm = (wave >> 1) * 64, wn = (wave & 1) * 64;
    const int rq = lane >> 4, fr = lane & 15;

    f32x4 acc[4][4] = {};

    const int srow = wave * 32 + (lane >> 2);
    const int scol = (lane & 3) * 8;
    const short* Ag = A + (size_t)row0 * K;
    const short* Bg = B + (size_t)col0 * K;

    for (int kt = 0; kt < K; kt += 32) {
#pragma unroll
        for (int i = 0; i < 2; i++) {
            __builtin_amdgcn_global_load_lds(
                (const __attribute__((address_space(1))) void*)(Ag + (size_t)(srow + i * 16) * K + kt + scol),
                (__attribute__((address_space(3))) void*)(As + (wave * 2 + i) * 512),
                16, 0, 0);
            __builtin_amdgcn_global_load_lds(
                (const __attribute__((address_space(1))) void*)(Bg + (size_t)(srow + i * 16) * K + kt + scol),
                (__attribute__((address_space(3))) void*)(Bs + (wave * 2 + i) * 512),
                16, 0, 0);
        }
        __syncthreads();
        bf16x8 af[4], bfr[4];
#pragma unroll
        for (int i = 0; i < 4; i++)
            af[i] = *(const bf16x8*)(As + (wm + i * 16 + fr) * 32 + rq * 8);
#pragma unroll
        for (int n = 0; n < 4; n++)
            bfr[n] = *(const bf16x8*)(Bs + (wn + n * 16 + fr) * 32 + rq * 8);
#pragma unroll
        for (int i = 0; i < 4; i++)
#pragma unroll
            for (int n = 0; n < 4; n++)
                acc[i][n] = __builtin_amdgcn_mfma_f32_16x16x32_bf16(af[i], bfr[n], acc[i][n], 0, 0, 0);
        __syncthreads();
    }

#pragma unroll
    for (int i = 0; i < 4; i++) {
#pragma unroll
        for (int n = 0; n < 4; n++) {
            int col = col0 + wn + n * 16 + fr;
            float bv = bias[col];
#pragma unroll
            for (int r = 0; r < 4; r++) {
                int row = row0 + wm + i * 16 + rq * 4 + r;
                size_t idx = (size_t)row * N + col;
                float v = acc[i][n][r] + bv;
                if (EPI == 0) {
                    ((short*)C)[idx] = f2b(v);
                } else if (EPI == 1) {
                    float* O = (float*)C;
                    O[idx] = O[idx] + v;
                } else {
                    float g = 0.5f * v * (1.0f + erff(v * 0.70710678118654752f));
                    ((short*)C)[idx] = f2b(g);
                }
            }
        }
    }
}

// ---------------- windowed attention: 1 wave per (window, head) ----------------
__global__ __launch_bounds__(64) void attn_win(const short* __restrict__ qkv,
                                               short* __restrict__ out) {
    const int win = blockIdx.x / NH;
    const int head = blockIdx.x % NH;
    __shared__ __align__(16) short Ks[WIN * 64];
    __shared__ __align__(16) short Vs[WIN * 64];
    __shared__ float Ps[64 * WIN];
    const int lane = threadIdx.x;
    const size_t rb = (size_t)win * WIN;
    const int qoff = head * 64;

    for (int i = lane; i < WIN * 8; i += 64) {
        int r = i >> 3, c = (i & 7) * 8;
        const short* kg = qkv + (rb + r) * 2304 + DMODEL + qoff + c;
        *(bf16x8*)(Ks + r * 64 + c) = *(const bf16x8*)kg;
        *(bf16x8*)(Vs + r * 64 + c) = *(const bf16x8*)(kg + DMODEL);
    }
    __syncthreads();
    if (lane < WIN) {
        float q[64];
        const short* qg = qkv + (rb + lane) * 2304 + qoff;
#pragma unroll
        for (int c = 0; c < 8; c++) {
            bf16x8 t = *(const bf16x8*)(qg + c * 8);
#pragma unroll
            for (int d = 0; d < 8; d++) q[c * 8 + d] = bf2f(t[d]);
        }
        float m = -1e30f;
        for (int j = 0; j < WIN; j++) {
            float a = 0.f;
#pragma unroll
            for (int c = 0; c < 8; c++) {
                bf16x8 kv = *(const bf16x8*)(Ks + j * 64 + c * 8);
#pragma unroll
                for (int d = 0; d < 8; d++) a += q[c * 8 + d] * bf2f(kv[d]);
            }
            a *= 0.125f;
            Ps[lane * WIN + j] = a;
            m = fmaxf(m, a);
        }
        float sum = 0.f;
        for (int j = 0; j < WIN; j++) {
            float p = __expf(Ps[lane * WIN + j] - m);
            Ps[lane * WIN + j] = p;
            sum += p;
        }
        float rinv = 1.f / sum;
        short* og = out + (rb + lane) * DMODEL + qoff;
        for (int c = 0; c < 8; c++) {
            float o[8] = {0.f, 0.f, 0.f, 0.f, 0.f, 0.f, 0.f, 0.f};
            for (int j = 0; j < WIN; j++) {
                float p = Ps[lane * WIN + j];
                bf16x8 vv = *(const bf16x8*)(Vs + j * 64 + c * 8);
#pragma unroll
                for (int d = 0; d < 8; d++) o[d] += p * bf2f(vv[d]);
            }
            bf16x8 ov;
#pragma unroll
            for (int d = 0; d < 8; d++) ov[d] = f2b(o[d] * rinv);
            *(bf16x8*)(og + c * 8) = ov;
        }
    }
}

extern "C" void kernel_launch(void* const* d_in, const int* in_sizes, int n_in,
                              void* d_out, int out_size, void* d_ws, size_t ws_size,
                              hipStream_t stream) {
    const float* x    = (const float*)d_in[0];
    const float* Wqkv = (const float*)d_in[1];
    const float* bqkv = (const float*)d_in[2];
    const float* Wo   = (const float*)d_in[3];
    const float* bo   = (const float*)d_in[4];
    const float* ln1w = (const float*)d_in[5];
    const float* ln1b = (const float*)d_in[6];
    const float* W1   = (const float*)d_in[7];
    const float* b1   = (const float*)d_in[8];
    const float* W2   = (const float*)d_in[9];
    const float* b2   = (const float*)d_in[10];
    const float* ln2w = (const float*)d_in[11];
    const float* ln2b = (const float*)d_in[12];

    const int M = MTOT;
    char* ws = (char*)d_ws;
    // layout: y/attn (38,535,168 B) | qkv/gelu big buffer (154,140,672 B) | bf16 weights
    short* ybf   = (short*)(ws);
    short* bigbf = (short*)(ws + 38535168);
    short* wqkvb = (short*)(ws + 38535168 + 154140672);
    short* wob   = wqkvb + (size_t)NLAYER * 2304 * 768;
    short* w1b   = wob + (size_t)NLAYER * 768 * 768;
    short* w2b   = w1b + (size_t)NLAYER * 3072 * 768;

    // h lives in d_out (fp32); initialize with x
    hipMemcpyAsync(d_out, (const void*)x, (size_t)M * DMODEL * sizeof(float),
                   hipMemcpyDeviceToDevice, stream);

    // weight conversions (every call; no persistent state)
    {
        size_t n;
        n = (size_t)NLAYER * 2304 * 768;
        cvt_f32_to_bf16<<<((int)(n / 8) + 255) / 256, 256, 0, stream>>>(Wqkv, wqkvb, (int)(n / 8));
        n = (size_t)NLAYER * 768 * 768;
        cvt_f32_to_bf16<<<((int)(n / 8) + 255) / 256, 256, 0, stream>>>(Wo, wob, (int)(n / 8));
        n = (size_t)NLAYER * 3072 * 768;
        cvt_f32_to_bf16<<<((int)(n / 8) + 255) / 256, 256, 0, stream>>>(W1, w1b, (int)(n / 8));
        n = (size_t)NLAYER * 768 * 3072;
        cvt_f32_to_bf16<<<((int)(n / 8) + 255) / 256, 256, 0, stream>>>(W2, w2b, (int)(n / 8));
    }

    float* h = (float*)d_out;
    for (int l = 0; l < NLAYER; l++) {
        // y = LN1(h)
        ln_to_bf16<<<M / 4, 256, 0, stream>>>(h, ln1w + l * DMODEL, ln1b + l * DMODEL, ybf);
        // qkv = y @ Wqkv^T + bqkv  (bf16 out)
        {
            dim3 g(2304 / 128, M / 128);
            gemm_bt<0><<<g, 256, 0, stream>>>(ybf, wqkvb + (size_t)l * 2304 * 768,
                                              bqkv + (size_t)l * 2304, bigbf, M, 2304, DMODEL);
        }
        // windowed attention (writes into ybf; y is dead)
        attn_win<<<(M / WIN) * NH, 64, 0, stream>>>(bigbf, ybf);
        // h += attn @ Wo^T + bo
        {
            dim3 g(768 / 128, M / 128);
            gemm_bt<1><<<g, 256, 0, stream>>>(ybf, wob + (size_t)l * 768 * 768,
                                              bo + (size_t)l * 768, h, M, 768, DMODEL);
        }
        // y2 = LN2(h)
        ln_to_bf16<<<M / 4, 256, 0, stream>>>(h, ln2w + l * DMODEL, ln2b + l * DMODEL, ybf);
        // g = gelu(y2 @ W1^T + b1)  (bf16 out, into big buffer)
        {
            dim3 g(3072 / 128, M / 128);
            gemm_bt<2><<<g, 256, 0, stream>>>(ybf, w1b + (size_t)l * 3072 * 768,
                                              b1 + (size_t)l * 3072, bigbf, M, 3072, DMODEL);
        }
        // h += g @ W2^T + b2
        {
            dim3 g(768 / 128, M / 128);
            gemm_bt<1><<<g, 256, 0, stream>>>(bigbf, w2b + (size_t)l * 768 * 3072,
                                              b2 + (size_t)l * 768, h, M, 768, 3072);
        }
    }
}

// Round 2
// 1821.770 us; speedup vs baseline: 1.0203x; 1.0203x over previous
//
#include <hip/hip_runtime.h>

#define MTOT 25088
#define DMODEL 768
#define NH 12
#define WIN 49
#define NLAYER 2

typedef short bf16x8 __attribute__((ext_vector_type(8)));
typedef float f32x4 __attribute__((ext_vector_type(4)));
typedef unsigned short u16x4 __attribute__((ext_vector_type(4)));

__device__ __forceinline__ float bf2f(short s) {
    return __uint_as_float(((unsigned)(unsigned short)s) << 16);
}
__device__ __forceinline__ short f2b(float f) {
    unsigned x = __float_as_uint(f);
    unsigned r = x + 0x7FFFu + ((x >> 16) & 1u);
    return (short)(r >> 16);
}

// ---------------- fp32 -> bf16 weight conversion ----------------
__global__ __launch_bounds__(256) void cvt_f32_to_bf16(const float* __restrict__ in,
                                                       short* __restrict__ out, int n8) {
    int i = blockIdx.x * 256 + threadIdx.x;
    if (i >= n8) return;
    const float4* p = (const float4*)in + (size_t)i * 2;
    float4 a = p[0], b = p[1];
    bf16x8 o;
    o[0] = f2b(a.x); o[1] = f2b(a.y); o[2] = f2b(a.z); o[3] = f2b(a.w);
    o[4] = f2b(b.x); o[5] = f2b(b.y); o[6] = f2b(b.z); o[7] = f2b(b.w);
    *((bf16x8*)out + i) = o;
}

// ---------------- LayerNorm (fp32 in, bf16 out), 1 wave per row ----------------
__global__ __launch_bounds__(256) void ln_to_bf16(const float* __restrict__ h,
                                                  const float* __restrict__ w,
                                                  const float* __restrict__ b,
                                                  short* __restrict__ y) {
    int wave = threadIdx.x >> 6, lane = threadIdx.x & 63;
    int row = blockIdx.x * 4 + wave;
    const float4* hp = (const float4*)(h + (size_t)row * DMODEL);
    float4 v[3];
    float s = 0.f, s2 = 0.f;
#pragma unroll
    for (int c = 0; c < 3; c++) {
        v[c] = hp[lane + 64 * c];
        s += v[c].x + v[c].y + v[c].z + v[c].w;
        s2 += v[c].x * v[c].x + v[c].y * v[c].y + v[c].z * v[c].z + v[c].w * v[c].w;
    }
#pragma unroll
    for (int off = 32; off > 0; off >>= 1) {
        s += __shfl_xor(s, off);
        s2 += __shfl_xor(s2, off);
    }
    float mean = s * (1.f / DMODEL);
    float var = s2 * (1.f / DMODEL) - mean * mean;
    float rstd = rsqrtf(var + 1e-5f);
#pragma unroll
    for (int c = 0; c < 3; c++) {
        float4 wv = ((const float4*)w)[lane + 64 * c];
        float4 bv = ((const float4*)b)[lane + 64 * c];
        u16x4 o;
        o[0] = (unsigned short)f2b((v[c].x - mean) * rstd * wv.x + bv.x);
        o[1] = (unsigned short)f2b((v[c].y - mean) * rstd * wv.y + bv.y);
        o[2] = (unsigned short)f2b((v[c].z - mean) * rstd * wv.z + bv.z);
        o[3] = (unsigned short)f2b((v[c].w - mean) * rstd * wv.w + bv.w);
        *(u16x4*)(y + (size_t)row * DMODEL + (size_t)(lane + 64 * c) * 4) = o;
    }
}

// ---------------- 256x256-tile 8-phase GEMM: C[M,N] = A[M,K] @ B[N,K]^T + bias ----------------
// EPI 0: out bf16 = v + bias ; EPI 1: fp32 C += v + bias ; EPI 2: out bf16 = gelu(v+bias)
// MF: row-frags per wave (8 -> BM=256, 4 -> BM=128). BN=256, BK=64 (2 K-halves of 32).
#define BAR() asm volatile("s_barrier" ::: "memory")
#define LGKM0() do { asm volatile("s_waitcnt lgkmcnt(0)" ::: "memory"); __builtin_amdgcn_sched_barrier(0); } while (0)

template <int EPI, int MF>
__global__ __launch_bounds__(512, 2)
void gemm256(const short* __restrict__ A, const short* __restrict__ B,
             const float* __restrict__ bias, void* __restrict__ C,
             int N, int K, int gx) {
    constexpr int ABYTES = MF * 2048;   // A bytes per (buf, khalf) region
    constexpr int BSOFF = 4 * ABYTES;   // Bs base offset
    __shared__ char lds[BSOFF + 65536];
    const int tid = threadIdx.x;
    const int wave = tid >> 6, lane = tid & 63;
    const int wr = wave >> 2, wc = wave & 3;
    const int fr = lane & 15, rq = lane >> 4;

    // bijective XCD swizzle (m204)
    int nwg = gridDim.x, orig = blockIdx.x;
    int q8 = nwg >> 3, r8 = nwg & 7;
    int xcd = orig & 7, lid = orig >> 3;
    int wg = (xcd < r8 ? xcd * (q8 + 1) : r8 * (q8 + 1) + (xcd - r8) * q8) + lid;
    const int bn = wg % gx, bm = wg / gx;
    const int row0 = bm * (MF * 32), col0 = bn * 256;
    const int nt = K >> 6;

    const short* Ag = A + (size_t)row0 * K;
    const short* Bg = B + (size_t)col0 * K;

#define STAGE_A(T, KH) do { int ts_ = ((T) < nt ? (T) : 0);                                        \
    _Pragma("unroll") for (int j = 0; j < MF / 4; j++) {                                           \
      int rr_ = (tid >> 2) + j * 128;                                                              \
      int ch_ = (tid & 3) ^ ((rr_ >> 1) & 3);                                                      \
      __builtin_amdgcn_global_load_lds(                                                            \
        (const __attribute__((address_space(1))) void*)(Ag + (size_t)rr_ * K + ts_ * 64 + (KH) * 32 + ch_ * 8), \
        (__attribute__((address_space(3))) void*)(lds + ((((T) & 1) * 2 * ABYTES) + (KH) * ABYTES + wave * 1024 + j * 8192)), \
        16, 0, 0); } } while (0)

#define STAGE_B(T, KH) do { int ts_ = ((T) < nt ? (T) : 0);                                        \
    _Pragma("unroll") for (int j = 0; j < 2; j++) {                                                \
      int rr_ = (tid >> 2) + j * 128;                                                              \
      int ch_ = (tid & 3) ^ ((rr_ >> 1) & 3);                                                      \
      __builtin_amdgcn_global_load_lds(                                                            \
        (const __attribute__((address_space(1))) void*)(Bg + (size_t)rr_ * K + ts_ * 64 + (KH) * 32 + ch_ * 8), \
        (__attribute__((address_space(3))) void*)(lds + (BSOFF + (((T) & 1) * 32768) + (KH) * 16384 + wave * 1024 + j * 8192)), \
        16, 0, 0); } } while (0)

#define LDA(m, KH, BUF) (*(const bf16x8*)(lds + (((BUF) * 2 * ABYTES) + (KH) * ABYTES +            \
    (((wr * (MF * 16) + (m) * 16 + fr) * 64 + rq * 16) ^ ((((wr * (MF * 16) + (m) * 16 + fr) >> 1) & 3) << 4)))))
#define LDB(n, KH, BUF) (*(const bf16x8*)(lds + (BSOFF + ((BUF) * 32768) + (KH) * 16384 +          \
    (((wc * 64 + (n) * 16 + fr) * 64 + rq * 16) ^ ((((wc * 64 + (n) * 16 + fr) >> 1) & 3) << 4)))))

#define VMW() do { if constexpr (MF == 8) asm volatile("s_waitcnt vmcnt(8)" ::: "memory");         \
                   else                   asm volatile("s_waitcnt vmcnt(6)" ::: "memory"); } while (0)

    f32x4 acc[MF][4] = {};

    // prologue: stage (0,k0), (0,k1), (1,k0) — 3 K-halves ahead
    STAGE_A(0, 0); STAGE_B(0, 0);
    STAGE_A(0, 1); STAGE_B(0, 1);
    STAGE_A(1, 0); STAGE_B(1, 0);
    VMW();
    BAR();

    for (int t = 0; t < nt; t++) {
        const int buf = t & 1;
        bf16x8 a[MF], b0, b1, b2, b3;
        // ---- P1 (khalf 0, cols 0-1) ----
#pragma unroll
        for (int m = 0; m < MF; m++) a[m] = LDA(m, 0, buf);
        b0 = LDB(0, 0, buf); b1 = LDB(1, 0, buf);
        STAGE_A(t + 1, 1);
        BAR(); LGKM0();
        __builtin_amdgcn_s_setprio(1);
#pragma unroll
        for (int m = 0; m < MF; m++) {
            acc[m][0] = __builtin_amdgcn_mfma_f32_16x16x32_bf16(a[m], b0, acc[m][0], 0, 0, 0);
            acc[m][1] = __builtin_amdgcn_mfma_f32_16x16x32_bf16(a[m], b1, acc[m][1], 0, 0, 0);
        }
        __builtin_amdgcn_s_setprio(0);
        BAR();
        // ---- P2 (khalf 0, cols 2-3) ----
        b2 = LDB(2, 0, buf); b3 = LDB(3, 0, buf);
        STAGE_B(t + 1, 1);
        VMW();
        BAR(); LGKM0();
        __builtin_amdgcn_s_setprio(1);
#pragma unroll
        for (int m = 0; m < MF; m++) {
            acc[m][2] = __builtin_amdgcn_mfma_f32_16x16x32_bf16(a[m], b2, acc[m][2], 0, 0, 0);
            acc[m][3] = __builtin_amdgcn_mfma_f32_16x16x32_bf16(a[m], b3, acc[m][3], 0, 0, 0);
        }
        __builtin_amdgcn_s_setprio(0);
        BAR();
        // ---- P3 (khalf 1, cols 0-1) ----
#pragma unroll
        for (int m = 0; m < MF; m++) a[m] = LDA(m, 1, buf);
        b0 = LDB(0, 1, buf); b1 = LDB(1, 1, buf);
        STAGE_A(t + 2, 0);
        BAR(); LGKM0();
        __builtin_amdgcn_s_setprio(1);
#pragma unroll
        for (int m = 0; m < MF; m++) {
            acc[m][0] = __builtin_amdgcn_mfma_f32_16x16x32_bf16(a[m], b0, acc[m][0], 0, 0, 0);
            acc[m][1] = __builtin_amdgcn_mfma_f32_16x16x32_bf16(a[m], b1, acc[m][1], 0, 0, 0);
        }
        __builtin_amdgcn_s_setprio(0);
        BAR();
        // ---- P4 (khalf 1, cols 2-3) ----
        b2 = LDB(2, 1, buf); b3 = LDB(3, 1, buf);
        STAGE_B(t + 2, 0);
        VMW();
        BAR(); LGKM0();
        __builtin_amdgcn_s_setprio(1);
#pragma unroll
        for (int m = 0; m < MF; m++) {
            acc[m][2] = __builtin_amdgcn_mfma_f32_16x16x32_bf16(a[m], b2, acc[m][2], 0, 0, 0);
            acc[m][3] = __builtin_amdgcn_mfma_f32_16x16x32_bf16(a[m], b3, acc[m][3], 0, 0, 0);
        }
        __builtin_amdgcn_s_setprio(0);
        BAR();
    }
    // drain outstanding LDS-targeted loads before workgroup can exit
    asm volatile("s_waitcnt vmcnt(0)" ::: "memory");

    // epilogue: C/D layout col=lane&15, row=(lane>>4)*4+reg
#pragma unroll
    for (int m = 0; m < MF; m++) {
#pragma unroll
        for (int n = 0; n < 4; n++) {
            int col = col0 + wc * 64 + n * 16 + fr;
            float bv = bias[col];
#pragma unroll
            for (int rg = 0; rg < 4; rg++) {
                int row = row0 + wr * (MF * 16) + m * 16 + rq * 4 + rg;
                size_t idx = (size_t)row * N + col;
                float v = acc[m][n][rg] + bv;
                if constexpr (EPI == 0) {
                    ((short*)C)[idx] = f2b(v);
                } else if constexpr (EPI == 1) {
                    float* O = (float*)C;
                    O[idx] = O[idx] + v;
                } else {
                    float g = 0.5f * v * (1.0f + erff(v * 0.70710678118654752f));
                    ((short*)C)[idx] = f2b(g);
                }
            }
        }
    }
#undef STAGE_A
#undef STAGE_B
#undef LDA
#undef LDB
#undef VMW
}

// ---------------- windowed attention: 1 wave per (window, head) ----------------
__global__ __launch_bounds__(64) void attn_win(const short* __restrict__ qkv,
                                               short* __restrict__ out) {
    const int win = blockIdx.x / NH;
    const int head = blockIdx.x % NH;
    __shared__ __align__(16) short Ks[WIN * 64];
    __shared__ __align__(16) short Vs[WIN * 64];
    __shared__ float Ps[64 * WIN];
    const int lane = threadIdx.x;
    const size_t rb = (size_t)win * WIN;
    const int qoff = head * 64;

    for (int i = lane; i < WIN * 8; i += 64) {
        int r = i >> 3, c = (i & 7) * 8;
        const short* kg = qkv + (rb + r) * 2304 + DMODEL + qoff + c;
        *(bf16x8*)(Ks + r * 64 + c) = *(const bf16x8*)kg;
        *(bf16x8*)(Vs + r * 64 + c) = *(const bf16x8*)(kg + DMODEL);
    }
    __syncthreads();
    if (lane < WIN) {
        float q[64];
        const short* qg = qkv + (rb + lane) * 2304 + qoff;
#pragma unroll
        for (int c = 0; c < 8; c++) {
            bf16x8 t = *(const bf16x8*)(qg + c * 8);
#pragma unroll
            for (int d = 0; d < 8; d++) q[c * 8 + d] = bf2f(t[d]);
        }
        float m = -1e30f;
        for (int j = 0; j < WIN; j++) {
            float a = 0.f;
#pragma unroll
            for (int c = 0; c < 8; c++) {
                bf16x8 kv = *(const bf16x8*)(Ks + j * 64 + c * 8);
#pragma unroll
                for (int d = 0; d < 8; d++) a += q[c * 8 + d] * bf2f(kv[d]);
            }
            a *= 0.125f;
            Ps[lane * WIN + j] = a;
            m = fmaxf(m, a);
        }
        float sum = 0.f;
        for (int j = 0; j < WIN; j++) {
            float p = __expf(Ps[lane * WIN + j] - m);
            Ps[lane * WIN + j] = p;
            sum += p;
        }
        float rinv = 1.f / sum;
        short* og = out + (rb + lane) * DMODEL + qoff;
        for (int c = 0; c < 8; c++) {
            float o[8] = {0.f, 0.f, 0.f, 0.f, 0.f, 0.f, 0.f, 0.f};
            for (int j = 0; j < WIN; j++) {
                float p = Ps[lane * WIN + j];
                bf16x8 vv = *(const bf16x8*)(Vs + j * 64 + c * 8);
#pragma unroll
                for (int d = 0; d < 8; d++) o[d] += p * bf2f(vv[d]);
            }
            bf16x8 ov;
#pragma unroll
            for (int d = 0; d < 8; d++) ov[d] = f2b(o[d] * rinv);
            *(bf16x8*)(og + c * 8) = ov;
        }
    }
}

extern "C" void kernel_launch(void* const* d_in, const int* in_sizes, int n_in,
                              void* d_out, int out_size, void* d_ws, size_t ws_size,
                              hipStream_t stream) {
    const float* x    = (const float*)d_in[0];
    const float* Wqkv = (const float*)d_in[1];
    const float* bqkv = (const float*)d_in[2];
    const float* Wo   = (const float*)d_in[3];
    const float* bo   = (const float*)d_in[4];
    const float* ln1w = (const float*)d_in[5];
    const float* ln1b = (const float*)d_in[6];
    const float* W1   = (const float*)d_in[7];
    const float* b1   = (const float*)d_in[8];
    const float* W2   = (const float*)d_in[9];
    const float* b2   = (const float*)d_in[10];
    const float* ln2w = (const float*)d_in[11];
    const float* ln2b = (const float*)d_in[12];

    const int M = MTOT;
    char* ws = (char*)d_ws;
    short* ybf   = (short*)(ws);
    short* bigbf = (short*)(ws + 38535168);
    short* wqkvb = (short*)(ws + 38535168 + 154140672);
    short* wob   = wqkvb + (size_t)NLAYER * 2304 * 768;
    short* w1b   = wob + (size_t)NLAYER * 768 * 768;
    short* w2b   = w1b + (size_t)NLAYER * 3072 * 768;

    hipMemcpyAsync(d_out, (const void*)x, (size_t)M * DMODEL * sizeof(float),
                   hipMemcpyDeviceToDevice, stream);

    {
        size_t n;
        n = (size_t)NLAYER * 2304 * 768;
        cvt_f32_to_bf16<<<((int)(n / 8) + 255) / 256, 256, 0, stream>>>(Wqkv, wqkvb, (int)(n / 8));
        n = (size_t)NLAYER * 768 * 768;
        cvt_f32_to_bf16<<<((int)(n / 8) + 255) / 256, 256, 0, stream>>>(Wo, wob, (int)(n / 8));
        n = (size_t)NLAYER * 3072 * 768;
        cvt_f32_to_bf16<<<((int)(n / 8) + 255) / 256, 256, 0, stream>>>(W1, w1b, (int)(n / 8));
        n = (size_t)NLAYER * 768 * 3072;
        cvt_f32_to_bf16<<<((int)(n / 8) + 255) / 256, 256, 0, stream>>>(W2, w2b, (int)(n / 8));
    }

    float* h = (float*)d_out;
    for (int l = 0; l < NLAYER; l++) {
        // y = LN1(h)
        ln_to_bf16<<<M / 4, 256, 0, stream>>>(h, ln1w + l * DMODEL, ln1b + l * DMODEL, ybf);
        // qkv = y @ Wqkv^T + bqkv  (bf16) : M x 2304, K=768, BM=256 -> grid 9*98
        gemm256<0, 8><<<dim3(9 * 98), 512, 0, stream>>>(
            ybf, wqkvb + (size_t)l * 2304 * 768, bqkv + (size_t)l * 2304, bigbf, 2304, 768, 9);
        // windowed attention (writes into ybf)
        attn_win<<<(M / WIN) * NH, 64, 0, stream>>>(bigbf, ybf);
        // h += attn @ Wo^T + bo : M x 768, K=768, BM=128 -> grid 3*196
        gemm256<1, 4><<<dim3(3 * 196), 512, 0, stream>>>(
            ybf, wob + (size_t)l * 768 * 768, bo + (size_t)l * 768, h, 768, 768, 3);
        // y2 = LN2(h)
        ln_to_bf16<<<M / 4, 256, 0, stream>>>(h, ln2w + l * DMODEL, ln2b + l * DMODEL, ybf);
        // g = gelu(y2 @ W1^T + b1) : M x 3072, K=768, BM=256 -> grid 12*98
        gemm256<2, 8><<<dim3(12 * 98), 512, 0, stream>>>(
            ybf, w1b + (size_t)l * 3072 * 768, b1 + (size_t)l * 3072, bigbf, 3072, 768, 12);
        // h += g @ W2^T + b2 : M x 768, K=3072, BM=128 -> grid 3*196
        gemm256<1, 4><<<dim3(3 * 196), 512, 0, stream>>>(
            bigbf, w2b + (size_t)l * 768 * 3072, b2 + (size_t)l * 768, h, 768, 3072, 3);
    }
}